// Round 4
// baseline (295.179 us; speedup 1.0000x reference)
//
#include <hip/hip_runtime.h>

// (B,C,D,H,W) = (2,64,32,64,64), R=2, NCH=125
#define B_ 2
#define C_ 64
#define D_ 32
#define H_ 64
#define W_ 64
#define NCH 125
#define HW_ 4096
#define DHW_ 131072
#define CDHW_ 8388608

// x2 tile per wave: 8 rows x 64 dwords, UNPADDED row-major = exactly the
// global_load_lds "uniform base + lane*16B" layout. 3 buffers, prefetch
// DISTANCE 2 (iter c DMAs slab c+2, gates vmcnt(6) = waits only for the
// triple issued two iterations ago). 4-dword guards front/back absorb the
// +-2-col halo reads of edge lanes (values masked).
// R1/R2 lesson: stride-64 has an 8-way read conflict but reg-staged
// conflict-free rewrite regressed (114->219us); keep DMA staging.
// R3 lesson: nt stores cut FETCH 300->95MB with ZERO time change -> kernel
// is latency-bound, not BW-bound; hence distance-2 + loads-only vmcnt window
// (all output stores moved to epilogue so the gate never drains a store).
#define TROWS 8
#define TBUF (TROWS * W_)          // 512 dwords per buffer
#define WREG (3 * TBUF)            // per-wave region (3 buffers)

typedef float f32x4 __attribute__((ext_vector_type(4)));

__device__ __attribute__((aligned(16))) const float g_zero[4] = {0.f, 0.f, 0.f, 0.f};

__device__ __forceinline__ void glds16(const float* g, float* l) {
    __builtin_amdgcn_global_load_lds(
        (const __attribute__((address_space(1))) void*)g,
        (__attribute__((address_space(3))) void*)l, 16, 0, 0);
}

// Output is write-once, never re-read: non-temporal stores keep the 131 MB
// write stream out of L2/L3 so inputs stay cache-resident (R3: FETCH 300->95MB).
__device__ __forceinline__ void nt_store4(float* p, float a, float b,
                                          float c, float d) {
    f32x4 v = {a, b, c, d};
    __builtin_nontemporal_store(v, (f32x4*)p);
}

// Live offsets form an L: s=i+j in [-4..4], last-write winner is
//   s<=0 -> (i,j)=(s+2,-2): rows y-2..y+2, cols x+2..x+5  (acc[4-k])
//   s>=0 -> (i,j)=(2,s-2) : row y-2, cols x+2-s           (acc[s+4])
// ch=(5s+h) mod 125 -> live {0..22}u{103..124}; 23..102 identically zero.
__global__ __launch_bounds__(128, 5) void cv_all(const float* __restrict__ x1,
                                                 const float* __restrict__ x2,
                                                 float* __restrict__ out)
{
    __shared__ __align__(16) float lds[4 + 2 * WREG + 4];

    const int tid  = threadIdx.y * 16 + threadIdx.x;
    const int lane = tid & 63;
    const int w    = tid >> 6;             // wave 0/1
    const int tx   = lane & 15;            // x quad
    const int lr0  = lane >> 4;            // 0..3: row within wave

    // XCD-grouped swizzle: XCD m owns d-slice [4m,4m+4) -> hh re-reads L2-hit
    const int lin     = blockIdx.x;                    // 0..2559
    const int logical = (lin & 7) * 320 + (lin >> 3);
    const int bz   = logical % 10;
    const int rest = logical / 10;
    const int y0   = (rest & 7) * 8;
    const int d    = rest >> 3;
    const int b    = bz / 5;
    const int hi   = bz - b * 5;           // 0..4
    const int hh   = hi - 2;               // depth shift in [-2,2]
    const int y0w  = y0 + 4 * w;           // wave's first output row
    const int y    = y0w + lr0;
    const int x    = tx * 4;
    const int zd   = d - hh;
    const bool zok = (zd >= 0) && (zd < D_);

    // staging sources: slot A = tile rows 0..3, slot B = rows 4..7
    const float* x2b = x2 + (size_t)b * CDHW_ + (size_t)(zok ? zd : 0) * HW_;
    const int q   = lane & 15;
    const int grA = y0w - 2 + (lane >> 4);             // [-2, 61]
    const int grB = y0w + 2 + (lane >> 4);             // [2, 67]
    const bool vA = zok && (grA >= 0);
    const bool vB = zok && (grB < H_);
    const float* pA = vA ? (x2b + grA * W_ + 4 * q) : g_zero;
    const float* pB = vB ? (x2b + grB * W_ + 4 * q) : g_zero;
    const int sA = vA ? DHW_ : 0;
    const int sB = vB ? DHW_ : 0;

    const int wbase = 4 + w * WREG;
    const float* p1 = x1 + (size_t)b * CDHW_ + (size_t)d * HW_ + (y * W_ + x);

    // ---- preamble: distance-2 fill. Issue ORDER matters for in-order vmcnt
    // accounting: iter-0 deps first (A0,B0,a0), then iter-1 deps (A1,B1,a1).
    glds16(pA, lds + wbase);                          // slab 0 -> buf 0
    glds16(pB, lds + wbase + TBUF / 2);
    float4 a0 = *(const float4*)p1;                   // x1 slab 0
    pA += sA; pB += sB;                               // -> slab 1
    glds16(pA, lds + wbase + TBUF);                   // slab 1 -> buf 1
    glds16(pB, lds + wbase + TBUF + TBUF / 2);
    float4 a1 = *(const float4*)(p1 + DHW_);          // x1 slab 1
    pA += sA; pB += sB;                               // -> slab 2

    float acc[9][4];
#pragma unroll
    for (int k = 0; k < 9; ++k)
#pragma unroll
        for (int j = 0; j < 4; ++j) acc[k][j] = 0.f;

    const bool lo_edge = (tx == 0);
    const bool hi_edge = (tx == 15);

#pragma unroll 2
    for (int c = 0; c < C_; ++c) {
        // 1. DMA slab c+2 -> buf (c+2)%3 (tail: re-DMA slab 63, harmless —
        //    it writes a buffer nothing reads anymore)
        float* dst = lds + wbase + ((c + 2) % 3) * TBUF;
        glds16(pA, dst);
        glds16(pB, dst + TBUF / 2);
        // 2. x1 slab c+2 (wraps at tail, harmless in-bounds load)
        float4 na = *(const float4*)(p1 + (size_t)((c + 2) & 63) * DHW_);
        if (c < 61) { pA += sA; pB += sB; }

        // 3. gate: 6 newest loads (iters c+1, c+2 triples) may be in flight;
        //    everything through x1(c) / DMA(c) — issued 2 iters ago — done.
        asm volatile("s_waitcnt vmcnt(6)" ::: "memory");

        // 4. compute c from buf c%3
        const float* Bb = lds + wbase + (c % 3) * TBUF;
        const float4 a = a0;
        float2 k0A, k0B;
#pragma unroll
        for (int k = 0; k < 5; ++k) {      // tile rows lr0..lr0+4 = y-2..y+2
            const float* pr = Bb + (lr0 + k) * W_ + x;
            const float2 cA = *(const float2*)(pr + 2);   // cols x+2,x+3
            float2 cB = *(const float2*)(pr + 4);         // cols x+4,x+5
            cB.x = hi_edge ? 0.f : cB.x;   // cols 64,65 don't exist
            cB.y = hi_edge ? 0.f : cB.y;
            if (k == 0) { k0A = cA; k0B = cB; }
            const int ai = 4 - k;
            acc[ai][0] += a.x * cA.x;
            acc[ai][1] += a.y * cA.y;
            acc[ai][2] += a.z * cB.x;
            acc[ai][3] += a.w * cB.y;
        }
        {                                  // row part: tile row lr0 = y-2
            const float* pr = Bb + lr0 * W_ + x;
            float2 rlA = *(const float2*)(pr - 2);        // cols x-2,x-1
            const float2 rlB = *(const float2*)(pr);      // cols x,x+1
            rlA.x = lo_edge ? 0.f : rlA.x; // cols -2,-1 don't exist
            rlA.y = lo_edge ? 0.f : rlA.y;
            const float r8[8] = {rlA.x, rlA.y, rlB.x, rlB.y,
                                 k0A.x, k0A.y, k0B.x, k0B.y};
#pragma unroll
            for (int s = 1; s <= 4; ++s) { // voxel x+v uses r8[4+v-s]
                const int ai = s + 4;
                acc[ai][0] += a.x * r8[4 - s];
                acc[ai][1] += a.y * r8[5 - s];
                acc[ai][2] += a.z * r8[6 - s];
                acc[ai][3] += a.w * r8[7 - s];
            }
        }
        a0 = a1; a1 = na;
    }

    // ---- epilogue: 16 dead-zero channels + 9 live channels (nt stores).
    // Stores kept out of the main loop so the vmcnt gate window is loads-only.
    float* obz = out + (size_t)b * NCH * DHW_ + (size_t)(23 + hi * 16) * DHW_
                     + (size_t)d * HW_ + (y * W_ + x);
#pragma unroll
    for (int j = 0; j < 16; ++j)
        nt_store4(obz + (size_t)j * DHW_, 0.f, 0.f, 0.f, 0.f);

    float* ob = out + (size_t)b * NCH * DHW_ + (size_t)d * HW_ + (y * W_ + x);
    const float inv = 1.0f / 125.0f;
#pragma unroll
    for (int k = 0; k < 9; ++k) {
        const int s = k - 4;
        int ch = 5 * s + hh;
        ch = (ch % NCH + NCH) % NCH;
        nt_store4(ob + (size_t)ch * DHW_,
                  acc[k][0] * inv, acc[k][1] * inv,
                  acc[k][2] * inv, acc[k][3] * inv);
    }
}

extern "C" void kernel_launch(void* const* d_in, const int* in_sizes, int n_in,
                              void* d_out, int out_size, void* d_ws, size_t ws_size,
                              hipStream_t stream) {
    const float* x1 = (const float*)d_in[0];
    const float* x2 = (const float*)d_in[1];
    float* out = (float*)d_out;
    // 2560 blocks x 2 waves = 20 waves/CU, all resident
    cv_all<<<dim3(2560, 1, 1), dim3(16, 8, 1), 0, stream>>>(x1, x2, out);
}